// Round 3
// baseline (202.590 us; speedup 1.0000x reference)
//
#include <hip/hip_runtime.h>
#include <hip/hip_bf16.h>
#include <stdint.h>

#define N_NODES 50000
#define KNB 32
#define DIM 256

typedef short s8v __attribute__((ext_vector_type(8)));
typedef float f4v __attribute__((ext_vector_type(4)));
typedef unsigned short u16;

__device__ inline float bf2f(u16 h) {
    unsigned int u = ((unsigned int)h) << 16;
    return __builtin_bit_cast(float, u);
}
__device__ inline u16 f2bf(float f) {
    unsigned int u = __builtin_bit_cast(unsigned int, f);
    unsigned int r = (u + 0x7fffu + ((u >> 16) & 1u)) >> 16;
    return (u16)r;
}

#define GLOAD16(gp, lp) __builtin_amdgcn_global_load_lds( \
    (const __attribute__((address_space(1))) unsigned int*)(gp), \
    (__attribute__((address_space(3))) unsigned int*)(lp), 16, 0, 0)

// Sliced feature layout: xbs[c][n][d2], c in [0,8), d2 in [0,32).
// Element offset = (c*N + n)*32 + d2. Each chunk c is a contiguous 3.2 MB
// region -> fits one XCD's 4 MB L2 when blocks are pinned via bid&7.

// ---------------- kernel 1: convert x -> sliced bf16, weights^T, esc --------
__global__ __launch_bounds__(256) void k_convert(
    const float* __restrict__ x, const float* __restrict__ Wc,
    const float* __restrict__ Wn, const float* __restrict__ edge,
    const int* __restrict__ adj, u16* __restrict__ xbs,
    u16* __restrict__ Wct, u16* __restrict__ Wnt, float* __restrict__ esc)
{
    int64_t tid = (int64_t)blockIdx.x * blockDim.x + threadIdx.x;
    int64_t stride = (int64_t)gridDim.x * blockDim.x;

    // x [N][256] f32 -> sliced bf16; item i = (n, d8), 8 dims each
    const int64_t nitems = (int64_t)N_NODES * 32;
    for (int64_t i = tid; i < nitems; i += stride) {
        int n = (int)(i >> 5), d8 = (int)(i & 31);
        int c = d8 >> 2, d2 = (d8 & 3) * 8;
        float4 v0 = ((const float4*)x)[i * 2];
        float4 v1 = ((const float4*)x)[i * 2 + 1];
        s8v o;
        o[0] = (short)f2bf(v0.x); o[1] = (short)f2bf(v0.y);
        o[2] = (short)f2bf(v0.z); o[3] = (short)f2bf(v0.w);
        o[4] = (short)f2bf(v1.x); o[5] = (short)f2bf(v1.y);
        o[6] = (short)f2bf(v1.z); o[7] = (short)f2bf(v1.w);
        *(s8v*)(xbs + ((int64_t)c * N_NODES + n) * 32 + d2) = o;
    }

    // weights -> bf16 transposed [col][k]
    for (int64_t i = tid; i < 256 * 256; i += stride) {
        int r = (int)(i >> 8), c = (int)(i & 255);   // W[r][c]
        Wct[c * 256 + r] = f2bf(Wc[i]);
        Wnt[c * 256 + r] = f2bf(Wn[i]);
    }

    // esc[n][2] = (1/nh) * sum_k edge[n][k][:]; one wave per node
    int lane = threadIdx.x & 63;
    int gw = (int)((blockIdx.x * 256 + threadIdx.x) >> 6);
    int nwaves = (int)((gridDim.x * 256) >> 6);
    for (int n = gw; n < N_NODES; n += nwaves) {
        float ev = edge[(int64_t)n * 64 + lane];
        ev += __shfl_xor(ev, 2);
        ev += __shfl_xor(ev, 4);
        ev += __shfl_xor(ev, 8);
        ev += __shfl_xor(ev, 16);
        ev += __shfl_xor(ev, 32);
        int a = (lane < 32) ? adj[n * 32 + lane] : -1;
        unsigned long long m = __ballot(lane < 32 && a != -1);
        float inv = 1.0f / fmaxf((float)__popcll(m), 1.0f);
        if (lane < 2) esc[n * 2 + lane] = ev * inv;
    }
}

// ---------------- kernel 2: sliced gather-sum (XCD-pinned chunks) -----------
// sbs[c][n][d2] = bf16( (1/nh) * sum_k xbs[c][adj[n][k]][d2] )
// One wave per (node, chunk): 2 loads x 16B/lane cover 32 neighbors x 64B.
__global__ __launch_bounds__(256) void k_gather(
    const u16* __restrict__ xbs, const int* __restrict__ adj,
    u16* __restrict__ sbs)
{
    int wv = threadIdx.x >> 6, lane = threadIdx.x & 63;
    int c = blockIdx.x & 7;                 // chunk == XCD (heuristic pin)
    int n = (int)(blockIdx.x >> 3) * 4 + wv;
    if (n >= N_NODES) return;

    int aidx = 0, valid = 0;
    if (lane < 32) {
        aidx = adj[n * 32 + lane];
        valid = (aidx != -1);
        if (aidx < 0) aidx += N_NODES;      // numpy-style wrap for padding
    }
    unsigned long long m = __ballot(lane < 32 && valid);
    float inv = 1.0f / fmaxf((float)__popcll(m), 1.0f);

    int k4 = lane >> 2, seg = lane & 3;     // 16 k-groups x 4 segs(16B)
    const u16* base = xbs + (int64_t)c * N_NODES * 32 + seg * 8;
    float acc[8] = {0.f, 0.f, 0.f, 0.f, 0.f, 0.f, 0.f, 0.f};
    #pragma unroll
    for (int it = 0; it < 2; ++it) {
        int idx = __shfl(aidx, it * 16 + k4);
        s8v v = *(const s8v*)(base + (int64_t)idx * 32);
        #pragma unroll
        for (int j = 0; j < 8; ++j) acc[j] += bf2f((u16)v[j]);
    }
    #pragma unroll
    for (int j = 0; j < 8; ++j) {
        acc[j] += __shfl_xor(acc[j], 4);
        acc[j] += __shfl_xor(acc[j], 8);
        acc[j] += __shfl_xor(acc[j], 16);
        acc[j] += __shfl_xor(acc[j], 32);
    }
    if (lane < 4) {                         // k4==0 lanes hold full sums
        s8v o;
        #pragma unroll
        for (int j = 0; j < 8; ++j) o[j] = (short)f2bf(acc[j] * inv);
        *(s8v*)(sbs + ((int64_t)c * N_NODES + n) * 32 + seg * 8) = o;
    }
}

// ---------------- kernel 3: LDS-staged K=512 bf16 MFMA GEMM + epilogue ------
// A = concat_K(xbs, sbs) (sliced layouts); B = concat_K(Wct, Wnt) (linear).
// BM=128, BN=128, BK=64. Tile rows are 128B, XOR-swizzled in 16B segs on the
// GLOBAL source (linear LDS dest for global_load_lds), unswizzled on ds_read.
__device__ inline void stage_A(u16* tile, const u16* src, int row0,
                               int c0, int wv, int lane)
{
    #pragma unroll
    for (int cc = 0; cc < 4; ++cc) {
        int idxbase = cc * 256 + wv * 64;      // wave-uniform
        int idx = idxbase + lane;
        int row = idx >> 3, seg = idx & 7;
        int gr = row0 + row; if (gr >= N_NODES) gr = N_NODES - 1;
        int srcseg = seg ^ (row & 7);
        int chunk = c0 + (srcseg >> 2);
        int d2 = (srcseg & 3) * 8;
        const u16* g = src + ((int64_t)chunk * N_NODES + gr) * 32 + d2;
        GLOAD16(g, (char*)tile + idxbase * 16);
    }
}
__device__ inline void stage_B(u16* tile, const u16* src, int col0,
                               int kboEl, int wv, int lane)
{
    #pragma unroll
    for (int cc = 0; cc < 4; ++cc) {
        int idxbase = cc * 256 + wv * 64;
        int idx = idxbase + lane;
        int row = idx >> 3, seg = idx & 7;
        int srcseg = seg ^ (row & 7);
        const u16* g = src + (int64_t)(col0 + row) * 256 + kboEl + srcseg * 8;
        GLOAD16(g, (char*)tile + idxbase * 16);
    }
}

__global__ __launch_bounds__(256) void k_gemm(
    const u16* __restrict__ xbs, const u16* __restrict__ sbs,
    const u16* __restrict__ Wct, const u16* __restrict__ Wnt,
    const float* __restrict__ esc, const float* __restrict__ We,
    const float* __restrict__ bias, float* __restrict__ out)
{
    __shared__ u16 Atile[2][128 * 64];
    __shared__ u16 Btile[2][128 * 64];

    int wv = threadIdx.x >> 6, lane = threadIdx.x & 63;
    int wm = wv >> 1, wn = wv & 1;
    int bm = blockIdx.x >> 1;          // M-tile (391)
    int nt = blockIdx.x & 1;           // N-tile (2)
    int mrow0 = bm * 128;
    int ncol0 = nt * 128;

    f4v acc[4][4];
    #pragma unroll
    for (int m = 0; m < 4; ++m)
        #pragma unroll
        for (int n = 0; n < 4; ++n) acc[m][n] = (f4v){0.f, 0.f, 0.f, 0.f};

    stage_A(Atile[0], xbs, mrow0, 0, wv, lane);
    stage_B(Btile[0], Wct, ncol0, 0, wv, lane);
    __syncthreads();

    int cur = 0;
    int lrow = wm * 64, lcol = wn * 64;
    int l15 = lane & 15, l4 = lane >> 4;

    for (int kb = 0; kb < 8; ++kb) {
        if (kb < 7) {
            int kn = kb + 1;
            const u16* As = (kn < 4) ? xbs : sbs;
            const u16* Bs = (kn < 4) ? Wct : Wnt;
            stage_A(Atile[cur ^ 1], As, mrow0, (kn & 3) * 2, wv, lane);
            stage_B(Btile[cur ^ 1], Bs, ncol0, (kn & 3) * 64, wv, lane);
        }
        const u16* At = Atile[cur];
        const u16* Bt = Btile[cur];
        #pragma unroll
        for (int ks = 0; ks < 2; ++ks) {
            s8v af[4], bfr[4];
            #pragma unroll
            for (int m = 0; m < 4; ++m) {
                int row = lrow + m * 16 + l15;
                int kb16 = ((ks * 4 + l4) * 16) ^ ((row & 7) << 4);
                af[m] = *(const s8v*)((const char*)At + row * 128 + kb16);
            }
            #pragma unroll
            for (int n = 0; n < 4; ++n) {
                int col = lcol + n * 16 + l15;
                int kb16 = ((ks * 4 + l4) * 16) ^ ((col & 7) << 4);
                bfr[n] = *(const s8v*)((const char*)Bt + col * 128 + kb16);
            }
            #pragma unroll
            for (int m = 0; m < 4; ++m)
                #pragma unroll
                for (int n = 0; n < 4; ++n)
                    acc[m][n] = __builtin_amdgcn_mfma_f32_16x16x32_bf16(
                        af[m], bfr[n], acc[m][n], 0, 0, 0);
        }
        __syncthreads();
        cur ^= 1;
    }

    // epilogue: C/D layout col=lane&15, row=(lane>>4)*4+reg
    #pragma unroll
    for (int m = 0; m < 4; ++m) {
        int r0 = mrow0 + lrow + m * 16 + l4 * 4;
        float e0[4], e1[4];
        #pragma unroll
        for (int r = 0; r < 4; ++r) {
            int row = r0 + r; if (row >= N_NODES) row = N_NODES - 1;
            e0[r] = esc[row * 2];
            e1[r] = esc[row * 2 + 1];
        }
        #pragma unroll
        for (int n = 0; n < 4; ++n) {
            int col = ncol0 + lcol + n * 16 + l15;
            float bc = bias[col];
            float w0 = We[col];
            float w1 = We[256 + col];
            #pragma unroll
            for (int r = 0; r < 4; ++r) {
                int row = r0 + r;
                if (row < N_NODES) {
                    float v = acc[m][n][r] + bc + e0[r] * w0 + e1[r] * w1;
                    out[(int64_t)row * 256 + col] = fmaxf(v, 0.0f);
                }
            }
        }
    }
}

extern "C" void kernel_launch(void* const* d_in, const int* in_sizes, int n_in,
                              void* d_out, int out_size, void* d_ws, size_t ws_size,
                              hipStream_t stream) {
    const float* x    = (const float*)d_in[0];
    const int*   adj  = (const int*)d_in[1];
    const float* edge = (const float*)d_in[2];
    const float* Wc   = (const float*)d_in[3];
    const float* Wn   = (const float*)d_in[4];
    const float* We   = (const float*)d_in[5];
    // d_in[6] = q : dead (softmax over size-1 axis == 1.0)
    const float* bias = (const float*)d_in[7];
    float* out = (float*)d_out;

    char* ws = (char*)d_ws;
    u16*   xbs = (u16*)(ws);                     // 8*N*32 bf16 = 25.6 MB
    u16*   sbs = (u16*)(ws + 25600000);          // 8*N*32 bf16 = 25.6 MB
    float* esc = (float*)(ws + 51200000);        // N*2 f32     = 0.4 MB
    u16*   Wct = (u16*)(ws + 51600000);          // 128 KB
    u16*   Wnt = (u16*)(ws + 51731072);          // 128 KB

    k_convert<<<2048, 256, 0, stream>>>(x, Wc, Wn, edge, adj, xbs, Wct, Wnt, esc);
    k_gather<<<((N_NODES + 3) / 4) * 8, 256, 0, stream>>>(xbs, adj, sbs);
    k_gemm<<<(N_NODES + 127) / 128 * 2, 256, 0, stream>>>(xbs, sbs, Wct, Wnt, esc, We, bias, out);
}

// Round 4
// 120.853 us; speedup vs baseline: 1.6763x; 1.6763x over previous
//
#include <hip/hip_runtime.h>
#include <hip/hip_bf16.h>
#include <stdint.h>

#define N_NODES 50000
#define KNB 32
#define DIM 256

typedef short s8v __attribute__((ext_vector_type(8)));
typedef float f4v __attribute__((ext_vector_type(4)));
typedef unsigned short u16;

__device__ inline float bf2f(u16 h) {
    unsigned int u = ((unsigned int)h) << 16;
    return __builtin_bit_cast(float, u);
}
__device__ inline u16 f2bf(float f) {
    unsigned int u = __builtin_bit_cast(unsigned int, f);
    unsigned int r = (u + 0x7fffu + ((u >> 16) & 1u)) >> 16;
    return (u16)r;
}

#define GLOAD16(gp, lp) __builtin_amdgcn_global_load_lds( \
    (const __attribute__((address_space(1))) unsigned int*)(gp), \
    (__attribute__((address_space(3))) unsigned int*)(lp), 16, 0, 0)

// Sliced feature layout: xbs[c][n][d2], c in [0,8), d2 in [0,32).
// Each chunk c is a contiguous 3.2 MB region -> L2-resident per XCD when
// blocks are pinned via blockIdx&7.

// ---- kernel 1: convert x -> sliced bf16, weights^T, esc, adj16, inv --------
__global__ __launch_bounds__(256) void k_convert(
    const float* __restrict__ x, const float* __restrict__ Wc,
    const float* __restrict__ Wn, const float* __restrict__ edge,
    const int* __restrict__ adj, u16* __restrict__ xbs,
    u16* __restrict__ Wct, u16* __restrict__ Wnt, float* __restrict__ esc,
    u16* __restrict__ adj16, float* __restrict__ invv)
{
    int64_t tid = (int64_t)blockIdx.x * blockDim.x + threadIdx.x;
    int64_t stride = (int64_t)gridDim.x * blockDim.x;

    // x [N][256] f32 -> sliced bf16; item i = (n, d8), 8 dims each
    const int64_t nitems = (int64_t)N_NODES * 32;
    for (int64_t i = tid; i < nitems; i += stride) {
        int n = (int)(i >> 5), d8 = (int)(i & 31);
        int c = d8 >> 2, d2 = (d8 & 3) * 8;
        float4 v0 = ((const float4*)x)[i * 2];
        float4 v1 = ((const float4*)x)[i * 2 + 1];
        s8v o;
        o[0] = (short)f2bf(v0.x); o[1] = (short)f2bf(v0.y);
        o[2] = (short)f2bf(v0.z); o[3] = (short)f2bf(v0.w);
        o[4] = (short)f2bf(v1.x); o[5] = (short)f2bf(v1.y);
        o[6] = (short)f2bf(v1.z); o[7] = (short)f2bf(v1.w);
        *(s8v*)(xbs + ((int64_t)c * N_NODES + n) * 32 + d2) = o;
    }

    // weights -> bf16 transposed [col][k]
    for (int64_t i = tid; i < 256 * 256; i += stride) {
        int r = (int)(i >> 8), c = (int)(i & 255);   // W[r][c]
        Wct[c * 256 + r] = f2bf(Wc[i]);
        Wnt[c * 256 + r] = f2bf(Wn[i]);
    }

    // per-node: esc = inv*sum_k edge, adj16 = wrapped u16 adj, invv = 1/nh
    int lane = threadIdx.x & 63;
    int gw = (int)((blockIdx.x * 256 + threadIdx.x) >> 6);
    int nwaves = (int)((gridDim.x * 256) >> 6);
    for (int n = gw; n < N_NODES; n += nwaves) {
        float ev = edge[(int64_t)n * 64 + lane];
        ev += __shfl_xor(ev, 2);
        ev += __shfl_xor(ev, 4);
        ev += __shfl_xor(ev, 8);
        ev += __shfl_xor(ev, 16);
        ev += __shfl_xor(ev, 32);
        int a = (lane < 32) ? adj[n * 32 + lane] : 0;
        unsigned long long m = __ballot(lane < 32 && a != -1);
        float inv = 1.0f / fmaxf((float)__popcll(m), 1.0f);
        if (lane < 32) {
            int w = a < 0 ? a + N_NODES : a;   // numpy wrap for -1 padding
            adj16[n * 32 + lane] = (u16)w;
        }
        if (lane < 2) esc[n * 2 + lane] = ev * inv;
        if (lane == 0) invv[n] = inv;
    }
}

// ---- kernel 2: sliced gather-sum, no reduce tree ---------------------------
// Wave = 16 nodes x 1 chunk. lane: node=lane>>2, seg=lane&3 (8 dims, 16B).
// 32 unrolled iterations: bpermute idx broadcast + 16B load + unpack/add.
__global__ __launch_bounds__(256) void k_gather(
    const u16* __restrict__ xbs, const u16* __restrict__ adj16,
    const float* __restrict__ invv, u16* __restrict__ sbs)
{
    int wv = threadIdx.x >> 6, lane = threadIdx.x & 63;
    int c = blockIdx.x & 7;                  // chunk == XCD (heuristic pin)
    int n0 = (int)(blockIdx.x >> 3) * 64 + wv * 16;
    if (n0 >= N_NODES) return;
    int node = lane >> 2, seg = lane & 3;
    int n = n0 + node;
    int nc = n < N_NODES ? n : N_NODES - 1;

    // preload this wave's 512 adj entries: lane holds (node, k=(lane&3)*8+j)
    int64_t aoff = (int64_t)n0 * 32 + lane * 8;
    if (aoff > (int64_t)N_NODES * 32 - 8) aoff = (int64_t)N_NODES * 32 - 8;
    int4 aw = *(const int4*)(adj16 + aoff);
    int a[8];
    a[0] = aw.x & 0xffff; a[1] = (int)(((unsigned)aw.x) >> 16);
    a[2] = aw.y & 0xffff; a[3] = (int)(((unsigned)aw.y) >> 16);
    a[4] = aw.z & 0xffff; a[5] = (int)(((unsigned)aw.z) >> 16);
    a[6] = aw.w & 0xffff; a[7] = (int)(((unsigned)aw.w) >> 16);

    float iv = invv[nc];

    const u16* base = xbs + (int64_t)c * N_NODES * 32 + seg * 8;
    float acc[8] = {0.f, 0.f, 0.f, 0.f, 0.f, 0.f, 0.f, 0.f};
    #pragma unroll
    for (int k = 0; k < 32; ++k) {
        int src = (lane & 60) | (k >> 3);        // quad-base | k-group lane
        int idx = __shfl(a[k & 7], src);         // a[k&7]: static index
        int4 w = *(const int4*)(base + (int64_t)idx * 32);
        unsigned u;
        u = (unsigned)w.x;
        acc[0] += __builtin_bit_cast(float, u << 16);
        acc[1] += __builtin_bit_cast(float, u & 0xffff0000u);
        u = (unsigned)w.y;
        acc[2] += __builtin_bit_cast(float, u << 16);
        acc[3] += __builtin_bit_cast(float, u & 0xffff0000u);
        u = (unsigned)w.z;
        acc[4] += __builtin_bit_cast(float, u << 16);
        acc[5] += __builtin_bit_cast(float, u & 0xffff0000u);
        u = (unsigned)w.w;
        acc[6] += __builtin_bit_cast(float, u << 16);
        acc[7] += __builtin_bit_cast(float, u & 0xffff0000u);
    }

    if (n < N_NODES) {
        s8v o;
        #pragma unroll
        for (int j = 0; j < 8; ++j) o[j] = (short)f2bf(acc[j] * iv);
        *(s8v*)(sbs + ((int64_t)c * N_NODES + n) * 32 + seg * 8) = o;
    }
}

// ---- kernel 3: LDS-staged K=512 bf16 MFMA GEMM + epilogue ------------------
__device__ inline void stage_A(u16* tile, const u16* src, int row0,
                               int c0, int wv, int lane)
{
    #pragma unroll
    for (int cc = 0; cc < 4; ++cc) {
        int idxbase = cc * 256 + wv * 64;      // wave-uniform
        int idx = idxbase + lane;
        int row = idx >> 3, seg = idx & 7;
        int gr = row0 + row; if (gr >= N_NODES) gr = N_NODES - 1;
        int srcseg = seg ^ (row & 7);
        int chunk = c0 + (srcseg >> 2);
        int d2 = (srcseg & 3) * 8;
        const u16* g = src + ((int64_t)chunk * N_NODES + gr) * 32 + d2;
        GLOAD16(g, (char*)tile + idxbase * 16);
    }
}
__device__ inline void stage_B(u16* tile, const u16* src, int col0,
                               int kboEl, int wv, int lane)
{
    #pragma unroll
    for (int cc = 0; cc < 4; ++cc) {
        int idxbase = cc * 256 + wv * 64;
        int idx = idxbase + lane;
        int row = idx >> 3, seg = idx & 7;
        int srcseg = seg ^ (row & 7);
        const u16* g = src + (int64_t)(col0 + row) * 256 + kboEl + srcseg * 8;
        GLOAD16(g, (char*)tile + idxbase * 16);
    }
}

__global__ __launch_bounds__(256) void k_gemm(
    const u16* __restrict__ xbs, const u16* __restrict__ sbs,
    const u16* __restrict__ Wct, const u16* __restrict__ Wnt,
    const float* __restrict__ esc, const float* __restrict__ We,
    const float* __restrict__ bias, float* __restrict__ out)
{
    __shared__ u16 Atile[2][128 * 64];
    __shared__ u16 Btile[2][128 * 64];

    int wv = threadIdx.x >> 6, lane = threadIdx.x & 63;
    int wm = wv >> 1, wn = wv & 1;
    int bm = blockIdx.x >> 1;          // M-tile (391)
    int nt = blockIdx.x & 1;           // N-tile (2)
    int mrow0 = bm * 128;
    int ncol0 = nt * 128;

    f4v acc[4][4];
    #pragma unroll
    for (int m = 0; m < 4; ++m)
        #pragma unroll
        for (int n = 0; n < 4; ++n) acc[m][n] = (f4v){0.f, 0.f, 0.f, 0.f};

    stage_A(Atile[0], xbs, mrow0, 0, wv, lane);
    stage_B(Btile[0], Wct, ncol0, 0, wv, lane);
    __syncthreads();

    int cur = 0;
    int lrow = wm * 64, lcol = wn * 64;
    int l15 = lane & 15, l4 = lane >> 4;

    for (int kb = 0; kb < 8; ++kb) {
        if (kb < 7) {
            int kn = kb + 1;
            const u16* As = (kn < 4) ? xbs : sbs;
            const u16* Bs = (kn < 4) ? Wct : Wnt;
            stage_A(Atile[cur ^ 1], As, mrow0, (kn & 3) * 2, wv, lane);
            stage_B(Btile[cur ^ 1], Bs, ncol0, (kn & 3) * 64, wv, lane);
        }
        const u16* At = Atile[cur];
        const u16* Bt = Btile[cur];
        #pragma unroll
        for (int ks = 0; ks < 2; ++ks) {
            s8v af[4], bfr[4];
            #pragma unroll
            for (int m = 0; m < 4; ++m) {
                int row = lrow + m * 16 + l15;
                int kb16 = ((ks * 4 + l4) * 16) ^ ((row & 7) << 4);
                af[m] = *(const s8v*)((const char*)At + row * 128 + kb16);
            }
            #pragma unroll
            for (int n = 0; n < 4; ++n) {
                int col = lcol + n * 16 + l15;
                int kb16 = ((ks * 4 + l4) * 16) ^ ((col & 7) << 4);
                bfr[n] = *(const s8v*)((const char*)Bt + col * 128 + kb16);
            }
            #pragma unroll
            for (int m = 0; m < 4; ++m)
                #pragma unroll
                for (int n = 0; n < 4; ++n)
                    acc[m][n] = __builtin_amdgcn_mfma_f32_16x16x32_bf16(
                        af[m], bfr[n], acc[m][n], 0, 0, 0);
        }
        __syncthreads();
        cur ^= 1;
    }

    // epilogue: C/D layout col=lane&15, row=(lane>>4)*4+reg
    #pragma unroll
    for (int m = 0; m < 4; ++m) {
        int r0 = mrow0 + lrow + m * 16 + l4 * 4;
        float e0[4], e1[4];
        #pragma unroll
        for (int r = 0; r < 4; ++r) {
            int row = r0 + r; if (row >= N_NODES) row = N_NODES - 1;
            e0[r] = esc[row * 2];
            e1[r] = esc[row * 2 + 1];
        }
        #pragma unroll
        for (int n = 0; n < 4; ++n) {
            int col = ncol0 + lcol + n * 16 + l15;
            float bc = bias[col];
            float w0 = We[col];
            float w1 = We[256 + col];
            #pragma unroll
            for (int r = 0; r < 4; ++r) {
                int row = r0 + r;
                if (row < N_NODES) {
                    float v = acc[m][n][r] + bc + e0[r] * w0 + e1[r] * w1;
                    out[(int64_t)row * 256 + col] = fmaxf(v, 0.0f);
                }
            }
        }
    }
}

extern "C" void kernel_launch(void* const* d_in, const int* in_sizes, int n_in,
                              void* d_out, int out_size, void* d_ws, size_t ws_size,
                              hipStream_t stream) {
    const float* x    = (const float*)d_in[0];
    const int*   adj  = (const int*)d_in[1];
    const float* edge = (const float*)d_in[2];
    const float* Wc   = (const float*)d_in[3];
    const float* Wn   = (const float*)d_in[4];
    const float* We   = (const float*)d_in[5];
    // d_in[6] = q : dead (softmax over size-1 axis == 1.0)
    const float* bias = (const float*)d_in[7];
    float* out = (float*)d_out;

    char* ws = (char*)d_ws;
    u16*   xbs   = (u16*)(ws);                   // 8*N*32 bf16 = 25.6 MB
    u16*   sbs   = (u16*)(ws + 25600000);        // 8*N*32 bf16 = 25.6 MB
    float* esc   = (float*)(ws + 51200000);      // N*2 f32     = 0.4 MB
    u16*   Wct   = (u16*)(ws + 51600000);        // 128 KB
    u16*   Wnt   = (u16*)(ws + 51731072);        // 128 KB
    u16*   adj16 = (u16*)(ws + 51862144);        // N*32 u16    = 3.2 MB
    float* invv  = (float*)(ws + 55062144);      // N f32       = 0.2 MB

    k_convert<<<2048, 256, 0, stream>>>(x, Wc, Wn, edge, adj, xbs, Wct, Wnt,
                                        esc, adj16, invv);
    k_gather<<<((N_NODES + 63) / 64) * 8, 256, 0, stream>>>(xbs, adj16, invv, sbs);
    k_gemm<<<(N_NODES + 127) / 128 * 2, 256, 0, stream>>>(xbs, sbs, Wct, Wnt, esc, We, bias, out);
}

// Round 5
// 119.854 us; speedup vs baseline: 1.6903x; 1.0083x over previous
//
#include <hip/hip_runtime.h>
#include <hip/hip_bf16.h>
#include <stdint.h>

#define N_NODES 50000
#define KNB 32
#define DIM 256

typedef short s8v __attribute__((ext_vector_type(8)));
typedef float f4v __attribute__((ext_vector_type(4)));
typedef unsigned short u16;

__device__ inline float bf2f(u16 h) {
    unsigned int u = ((unsigned int)h) << 16;
    return __builtin_bit_cast(float, u);
}
__device__ inline u16 f2bf(float f) {
    unsigned int u = __builtin_bit_cast(unsigned int, f);
    unsigned int r = (u + 0x7fffu + ((u >> 16) & 1u)) >> 16;
    return (u16)r;
}

#define GLOAD16(gp, lp) __builtin_amdgcn_global_load_lds( \
    (const __attribute__((address_space(1))) unsigned int*)(gp), \
    (__attribute__((address_space(3))) unsigned int*)(lp), 16, 0, 0)

// Sliced feature layout: xbs[c][n][d2], c in [0,8), d2 in [0,32).
// Each chunk c is a contiguous 3.2 MB region -> L2-resident per XCD when
// blocks are pinned via blockIdx&7.

// ---- kernel 1: convert x -> sliced bf16, weights^T, esc, adj16, inv --------
__global__ __launch_bounds__(256) void k_convert(
    const float* __restrict__ x, const float* __restrict__ Wc,
    const float* __restrict__ Wn, const float* __restrict__ edge,
    const int* __restrict__ adj, u16* __restrict__ xbs,
    u16* __restrict__ Wct, u16* __restrict__ Wnt, float* __restrict__ esc,
    u16* __restrict__ adj16, float* __restrict__ invv)
{
    int64_t tid = (int64_t)blockIdx.x * blockDim.x + threadIdx.x;
    int64_t stride = (int64_t)gridDim.x * blockDim.x;

    // x [N][256] f32 -> sliced bf16; item i = (n, d8), 8 dims each
    const int64_t nitems = (int64_t)N_NODES * 32;
    for (int64_t i = tid; i < nitems; i += stride) {
        int n = (int)(i >> 5), d8 = (int)(i & 31);
        int c = d8 >> 2, d2 = (d8 & 3) * 8;
        float4 v0 = ((const float4*)x)[i * 2];
        float4 v1 = ((const float4*)x)[i * 2 + 1];
        s8v o;
        o[0] = (short)f2bf(v0.x); o[1] = (short)f2bf(v0.y);
        o[2] = (short)f2bf(v0.z); o[3] = (short)f2bf(v0.w);
        o[4] = (short)f2bf(v1.x); o[5] = (short)f2bf(v1.y);
        o[6] = (short)f2bf(v1.z); o[7] = (short)f2bf(v1.w);
        *(s8v*)(xbs + ((int64_t)c * N_NODES + n) * 32 + d2) = o;
    }

    // weights -> bf16 transposed [col][k]
    for (int64_t i = tid; i < 256 * 256; i += stride) {
        int r = (int)(i >> 8), c = (int)(i & 255);   // W[r][c]
        Wct[c * 256 + r] = f2bf(Wc[i]);
        Wnt[c * 256 + r] = f2bf(Wn[i]);
    }

    // per-node: esc = inv*sum_k edge, adj16 = wrapped u16 adj, invv = 1/nh
    int lane = threadIdx.x & 63;
    int gw = (int)((blockIdx.x * 256 + threadIdx.x) >> 6);
    int nwaves = (int)((gridDim.x * 256) >> 6);
    for (int n = gw; n < N_NODES; n += nwaves) {
        float ev = edge[(int64_t)n * 64 + lane];
        ev += __shfl_xor(ev, 2);
        ev += __shfl_xor(ev, 4);
        ev += __shfl_xor(ev, 8);
        ev += __shfl_xor(ev, 16);
        ev += __shfl_xor(ev, 32);
        int a = (lane < 32) ? adj[n * 32 + lane] : 0;
        unsigned long long m = __ballot(lane < 32 && a != -1);
        float inv = 1.0f / fmaxf((float)__popcll(m), 1.0f);
        if (lane < 32) {
            int w = a < 0 ? a + N_NODES : a;   // numpy wrap for -1 padding
            adj16[n * 32 + lane] = (u16)w;
        }
        if (lane < 2) esc[n * 2 + lane] = ev * inv;
        if (lane == 0) invv[n] = inv;
    }
}

// ---- kernel 2: sliced gather-sum, explicit 8-deep load pipeline ------------
// Wave = 16 nodes x 1 chunk. lane: node=lane>>2, seg=lane&3 (8 dims, 16B).
// buf[8] keeps 8 independent dwordx4 gather loads in flight (all indices
// static after unroll -> stays in VGPRs, compiler emits counted vmcnt waits).
__global__ __launch_bounds__(256) void k_gather(
    const u16* __restrict__ xbs, const u16* __restrict__ adj16,
    const float* __restrict__ invv, u16* __restrict__ sbs)
{
    int wv = threadIdx.x >> 6, lane = threadIdx.x & 63;
    int c = blockIdx.x & 7;                  // chunk == XCD (heuristic pin)
    int n0 = (int)(blockIdx.x >> 3) * 64 + wv * 16;
    if (n0 >= N_NODES) return;
    int node = lane >> 2, seg = lane & 3;
    int n = n0 + node;
    int nc = n < N_NODES ? n : N_NODES - 1;

    // preload this wave's 512 adj entries: lane holds (node=lane>>2, k=(lane&3)*8+j)
    int64_t aoff = (int64_t)n0 * 32 + lane * 8;
    int4 aw = *(const int4*)(adj16 + aoff);
    int a[8];
    a[0] = aw.x & 0xffff; a[1] = (int)(((unsigned)aw.x) >> 16);
    a[2] = aw.y & 0xffff; a[3] = (int)(((unsigned)aw.y) >> 16);
    a[4] = aw.z & 0xffff; a[5] = (int)(((unsigned)aw.z) >> 16);
    a[6] = aw.w & 0xffff; a[7] = (int)(((unsigned)aw.w) >> 16);

    float iv = invv[nc];
    const u16* base = xbs + (int64_t)c * N_NODES * 32 + seg * 8;

    // prologue: issue loads for k = 0..7
    int4 buf[8];
    #pragma unroll
    for (int j = 0; j < 8; ++j) {
        int idx = __shfl(a[j & 7], (lane & 60) | (j >> 3));
        buf[j] = *(const int4*)(base + (int64_t)idx * 32);
    }

    float acc[8] = {0.f, 0.f, 0.f, 0.f, 0.f, 0.f, 0.f, 0.f};
    #pragma unroll
    for (int k = 0; k < 32; ++k) {
        int4 w = buf[k & 7];
        if (k < 24) {
            int kn = k + 8;
            int idx = __shfl(a[kn & 7], (lane & 60) | (kn >> 3));
            buf[k & 7] = *(const int4*)(base + (int64_t)idx * 32);
        }
        unsigned u;
        u = (unsigned)w.x;
        acc[0] += __builtin_bit_cast(float, u << 16);
        acc[1] += __builtin_bit_cast(float, u & 0xffff0000u);
        u = (unsigned)w.y;
        acc[2] += __builtin_bit_cast(float, u << 16);
        acc[3] += __builtin_bit_cast(float, u & 0xffff0000u);
        u = (unsigned)w.z;
        acc[4] += __builtin_bit_cast(float, u << 16);
        acc[5] += __builtin_bit_cast(float, u & 0xffff0000u);
        u = (unsigned)w.w;
        acc[6] += __builtin_bit_cast(float, u << 16);
        acc[7] += __builtin_bit_cast(float, u & 0xffff0000u);
    }

    if (n < N_NODES) {
        s8v o;
        #pragma unroll
        for (int j = 0; j < 8; ++j) o[j] = (short)f2bf(acc[j] * iv);
        *(s8v*)(sbs + ((int64_t)c * N_NODES + n) * 32 + seg * 8) = o;
    }
}

// ---- kernel 3: LDS-staged K=512 bf16 MFMA GEMM + epilogue ------------------
__device__ inline void stage_A(u16* tile, const u16* src, int row0,
                               int c0, int wv, int lane)
{
    #pragma unroll
    for (int cc = 0; cc < 4; ++cc) {
        int idxbase = cc * 256 + wv * 64;      // wave-uniform
        int idx = idxbase + lane;
        int row = idx >> 3, seg = idx & 7;
        int gr = row0 + row; if (gr >= N_NODES) gr = N_NODES - 1;
        int srcseg = seg ^ (row & 7);
        int chunk = c0 + (srcseg >> 2);
        int d2 = (srcseg & 3) * 8;
        const u16* g = src + ((int64_t)chunk * N_NODES + gr) * 32 + d2;
        GLOAD16(g, (char*)tile + idxbase * 16);
    }
}
__device__ inline void stage_B(u16* tile, const u16* src, int col0,
                               int kboEl, int wv, int lane)
{
    #pragma unroll
    for (int cc = 0; cc < 4; ++cc) {
        int idxbase = cc * 256 + wv * 64;
        int idx = idxbase + lane;
        int row = idx >> 3, seg = idx & 7;
        int srcseg = seg ^ (row & 7);
        const u16* g = src + (int64_t)(col0 + row) * 256 + kboEl + srcseg * 8;
        GLOAD16(g, (char*)tile + idxbase * 16);
    }
}

__global__ __launch_bounds__(256) void k_gemm(
    const u16* __restrict__ xbs, const u16* __restrict__ sbs,
    const u16* __restrict__ Wct, const u16* __restrict__ Wnt,
    const float* __restrict__ esc, const float* __restrict__ We,
    const float* __restrict__ bias, float* __restrict__ out)
{
    __shared__ u16 Atile[2][128 * 64];
    __shared__ u16 Btile[2][128 * 64];

    int wv = threadIdx.x >> 6, lane = threadIdx.x & 63;
    int wm = wv >> 1, wn = wv & 1;
    int bm = blockIdx.x >> 1;          // M-tile (391)
    int nt = blockIdx.x & 1;           // N-tile (2)
    int mrow0 = bm * 128;
    int ncol0 = nt * 128;

    f4v acc[4][4];
    #pragma unroll
    for (int m = 0; m < 4; ++m)
        #pragma unroll
        for (int n = 0; n < 4; ++n) acc[m][n] = (f4v){0.f, 0.f, 0.f, 0.f};

    stage_A(Atile[0], xbs, mrow0, 0, wv, lane);
    stage_B(Btile[0], Wct, ncol0, 0, wv, lane);
    __syncthreads();

    int cur = 0;
    int lrow = wm * 64, lcol = wn * 64;
    int l15 = lane & 15, l4 = lane >> 4;

    for (int kb = 0; kb < 8; ++kb) {
        if (kb < 7) {
            int kn = kb + 1;
            const u16* As = (kn < 4) ? xbs : sbs;
            const u16* Bs = (kn < 4) ? Wct : Wnt;
            stage_A(Atile[cur ^ 1], As, mrow0, (kn & 3) * 2, wv, lane);
            stage_B(Btile[cur ^ 1], Bs, ncol0, (kn & 3) * 64, wv, lane);
        }
        const u16* At = Atile[cur];
        const u16* Bt = Btile[cur];
        #pragma unroll
        for (int ks = 0; ks < 2; ++ks) {
            s8v af[4], bfr[4];
            #pragma unroll
            for (int m = 0; m < 4; ++m) {
                int row = lrow + m * 16 + l15;
                int kb16 = ((ks * 4 + l4) * 16) ^ ((row & 7) << 4);
                af[m] = *(const s8v*)((const char*)At + row * 128 + kb16);
            }
            #pragma unroll
            for (int n = 0; n < 4; ++n) {
                int col = lcol + n * 16 + l15;
                int kb16 = ((ks * 4 + l4) * 16) ^ ((col & 7) << 4);
                bfr[n] = *(const s8v*)((const char*)Bt + col * 128 + kb16);
            }
            #pragma unroll
            for (int m = 0; m < 4; ++m)
                #pragma unroll
                for (int n = 0; n < 4; ++n)
                    acc[m][n] = __builtin_amdgcn_mfma_f32_16x16x32_bf16(
                        af[m], bfr[n], acc[m][n], 0, 0, 0);
        }
        __syncthreads();
        cur ^= 1;
    }

    // epilogue: C/D layout col=lane&15, row=(lane>>4)*4+reg
    #pragma unroll
    for (int m = 0; m < 4; ++m) {
        int r0 = mrow0 + lrow + m * 16 + l4 * 4;
        float e0[4], e1[4];
        #pragma unroll
        for (int r = 0; r < 4; ++r) {
            int row = r0 + r; if (row >= N_NODES) row = N_NODES - 1;
            e0[r] = esc[row * 2];
            e1[r] = esc[row * 2 + 1];
        }
        #pragma unroll
        for (int n = 0; n < 4; ++n) {
            int col = ncol0 + lcol + n * 16 + l15;
            float bc = bias[col];
            float w0 = We[col];
            float w1 = We[256 + col];
            #pragma unroll
            for (int r = 0; r < 4; ++r) {
                int row = r0 + r;
                if (row < N_NODES) {
                    float v = acc[m][n][r] + bc + e0[r] * w0 + e1[r] * w1;
                    out[(int64_t)row * 256 + col] = fmaxf(v, 0.0f);
                }
            }
        }
    }
}

extern "C" void kernel_launch(void* const* d_in, const int* in_sizes, int n_in,
                              void* d_out, int out_size, void* d_ws, size_t ws_size,
                              hipStream_t stream) {
    const float* x    = (const float*)d_in[0];
    const int*   adj  = (const int*)d_in[1];
    const float* edge = (const float*)d_in[2];
    const float* Wc   = (const float*)d_in[3];
    const float* Wn   = (const float*)d_in[4];
    const float* We   = (const float*)d_in[5];
    // d_in[6] = q : dead (softmax over size-1 axis == 1.0)
    const float* bias = (const float*)d_in[7];
    float* out = (float*)d_out;

    char* ws = (char*)d_ws;
    u16*   xbs   = (u16*)(ws);                   // 8*N*32 bf16 = 25.6 MB
    u16*   sbs   = (u16*)(ws + 25600000);        // 8*N*32 bf16 = 25.6 MB
    float* esc   = (float*)(ws + 51200000);      // N*2 f32     = 0.4 MB
    u16*   Wct   = (u16*)(ws + 51600000);        // 128 KB
    u16*   Wnt   = (u16*)(ws + 51731072);        // 128 KB
    u16*   adj16 = (u16*)(ws + 51862144);        // N*32 u16    = 3.2 MB
    float* invv  = (float*)(ws + 55062144);      // N f32       = 0.2 MB

    k_convert<<<2048, 256, 0, stream>>>(x, Wc, Wn, edge, adj, xbs, Wct, Wnt,
                                        esc, adj16, invv);
    k_gather<<<((N_NODES + 63) / 64) * 8, 256, 0, stream>>>(xbs, adj16, invv, sbs);
    k_gemm<<<(N_NODES + 127) / 128 * 2, 256, 0, stream>>>(xbs, sbs, Wct, Wnt, esc, We, bias, out);
}